// Round 10
// baseline (1063.841 us; speedup 1.0000x reference)
//
#include <hip/hip_runtime.h>
#include <hip/hip_fp16.h>
#include <cstdint>
#include <cstddef>

// Problem constants (reference: N=4, P1=P2=2048, D=64, eps=0.1, 50 iters)
#define NB 4
#define P1 2048
#define P2 2048
#define DD 64
#define ITER 50
#define EPS 0.1f
#define INV_EPS 10.0f          // 1.0f/0.1f rounds to exactly 10.0f
#define THRESH 0.1f
// log(1/2048 + 1e-8) in fp32
#define LOG_MU -7.6245985f
#define ELOG (-0.76245985f)    // EPS * LOG_MU (== EPS * LOG_NU)
#define MU_VAL 0.00048829125f  // exp(LOG_MU) = 1/2048 + 1e-8
#define ERRSLOTS 32
#define RP (P2 / 4)            // float4s per fp32 row
#define RP16 (P2 / 8)          // uint4s (8 halfs) per fp16 row = 256
#define PCHUNKS 128            // iter blocks per batch (16 rows each)

// ---------------------------------------------------------------------------
// prep0: S = M + M^T, zero err accumulators, init active flags, zero cost out
// ---------------------------------------------------------------------------
__global__ void prep0(const float* __restrict__ M, float* __restrict__ S,
                      float* __restrict__ errAcc, int* __restrict__ active,
                      float* __restrict__ cost) {
    int t = threadIdx.x;
    for (int k = t; k < DD * DD; k += 256) {
        int d = k >> 6, e = k & 63;
        S[k] = M[d * DD + e] + M[e * DD + d];
    }
    for (int k = t; k < ITER * ERRSLOTS; k += 256) errAcc[k] = 0.0f;
    if (t < 64) active[t] = (t == 0) ? 1 : 0;
    if (t < NB) cost[t] = 0.0f;
}

// ---------------------------------------------------------------------------
// prep1: one wave per row. x-rows: xS = x@S, dx = 0.5*x·(Sx), u=0.
//        y-rows: dy = 0.5*y·(Sy), v=0.
// ---------------------------------------------------------------------------
__global__ __launch_bounds__(256) void prep1(const float* __restrict__ x,
                                             const float* __restrict__ y,
                                             const float* __restrict__ S,
                                             float* __restrict__ xS,
                                             float* __restrict__ dx,
                                             float* __restrict__ dy,
                                             float* __restrict__ u,
                                             float* __restrict__ v) {
    __shared__ float Sl[DD * DD];
    int t = threadIdx.x;
    for (int k = t; k < DD * DD; k += 256) Sl[k] = S[k];
    __syncthreads();
    int wave = t >> 6, lane = t & 63;
    int r = blockIdx.x * 4 + wave;          // 0 .. N*(P1+P2)-1
    bool isX = r < NB * P1;
    const float* src = isX ? x : y;
    int rr = isX ? r : r - NB * P1;
    float xv = src[(size_t)rr * DD + lane];
    float acc = 0.0f;
    #pragma unroll
    for (int d = 0; d < DD; ++d) {
        float xd = __shfl(xv, d, 64);
        acc = fmaf(xd, Sl[d * DD + lane], acc);
    }
    float p = acc * xv;
    #pragma unroll
    for (int o = 32; o; o >>= 1) p += __shfl_xor(p, o, 64);
    if (isX) {
        xS[(size_t)rr * DD + lane] = acc;
        if (lane == 0) { dx[rr] = 0.5f * p; u[rr] = 0.0f; }
    } else {
        if (lane == 0) { dy[rr] = 0.5f * p; v[rr] = 0.0f; }
    }
}

// ---------------------------------------------------------------------------
// gemmC: C[n,i,j] = dx[n,i] + dy[n,j] - sum_e xS[n,i,e]*y[n,j,e]
// Also writes a packed fp16 copy C16 (if non-null) for the iteration path.
// ---------------------------------------------------------------------------
__global__ __launch_bounds__(256) void gemmC(const float* __restrict__ xS,
                                             const float* __restrict__ y,
                                             const float* __restrict__ dx,
                                             const float* __restrict__ dy,
                                             float* __restrict__ C,
                                             unsigned short* __restrict__ C16h) {
    __shared__ float xs[64][68];
    __shared__ float ys[64][68];
    int n = blockIdx.z;
    int i0 = blockIdx.y * 64, j0 = blockIdx.x * 64;
    int t = threadIdx.x;

    #pragma unroll
    for (int k = 0; k < 4; ++k) {
        int f = t + 256 * k;       // 0..1023
        int row = f >> 4;          // 0..63
        int c4 = f & 15;           // 0..15
        float4 a = ((const float4*)xS)[((size_t)(n * P1 + i0 + row)) * (DD / 4) + c4];
        xs[4 * c4 + 0][row] = a.x; xs[4 * c4 + 1][row] = a.y;
        xs[4 * c4 + 2][row] = a.z; xs[4 * c4 + 3][row] = a.w;
        float4 b = ((const float4*)y)[((size_t)(n * P2 + j0 + row)) * (DD / 4) + c4];
        ys[4 * c4 + 0][row] = b.x; ys[4 * c4 + 1][row] = b.y;
        ys[4 * c4 + 2][row] = b.z; ys[4 * c4 + 3][row] = b.w;
    }
    __syncthreads();

    int tx = t & 15, ty = t >> 4;
    float acc[4][4] = {};
    #pragma unroll
    for (int e = 0; e < 64; ++e) {
        float4 a = *(const float4*)&xs[e][4 * ty];
        float4 b = *(const float4*)&ys[e][4 * tx];
        acc[0][0] = fmaf(a.x, b.x, acc[0][0]); acc[0][1] = fmaf(a.x, b.y, acc[0][1]);
        acc[0][2] = fmaf(a.x, b.z, acc[0][2]); acc[0][3] = fmaf(a.x, b.w, acc[0][3]);
        acc[1][0] = fmaf(a.y, b.x, acc[1][0]); acc[1][1] = fmaf(a.y, b.y, acc[1][1]);
        acc[1][2] = fmaf(a.y, b.z, acc[1][2]); acc[1][3] = fmaf(a.y, b.w, acc[1][3]);
        acc[2][0] = fmaf(a.z, b.x, acc[2][0]); acc[2][1] = fmaf(a.z, b.y, acc[2][1]);
        acc[2][2] = fmaf(a.z, b.z, acc[2][2]); acc[2][3] = fmaf(a.z, b.w, acc[2][3]);
        acc[3][0] = fmaf(a.w, b.x, acc[3][0]); acc[3][1] = fmaf(a.w, b.y, acc[3][1]);
        acc[3][2] = fmaf(a.w, b.z, acc[3][2]); acc[3][3] = fmaf(a.w, b.w, acc[3][3]);
    }

    int iBase = i0 + ty * 4, jBase = j0 + tx * 4;
    float4 dy4 = *(const float4*)&dy[n * P2 + jBase];
    #pragma unroll
    for (int r = 0; r < 4; ++r) {
        float dxv = dx[n * P1 + iBase + r];
        float4 o;
        o.x = dxv + dy4.x - acc[r][0];
        o.y = dxv + dy4.y - acc[r][1];
        o.z = dxv + dy4.z - acc[r][2];
        o.w = dxv + dy4.w - acc[r][3];
        size_t idx = ((size_t)(n * P1 + iBase + r)) * P2 + jBase;
        *(float4*)&C[idx] = o;
        if (C16h) {
            __half2 h01 = __floats2half2_rn(o.x, o.y);
            __half2 h23 = __floats2half2_rn(o.z, o.w);
            uint2 pk;
            pk.x = *reinterpret_cast<unsigned int*>(&h01);
            pk.y = *reinterpret_cast<unsigned int*>(&h23);
            *reinterpret_cast<uint2*>(&C16h[idx]) = pk;
        }
    }
}

// ---------------------------------------------------------------------------
// Shared helpers
// ---------------------------------------------------------------------------
__device__ __forceinline__ void load_row8(float4 dst[8], const float4* base, int lane) {
    #pragma unroll
    for (int k = 0; k < 8; ++k) dst[k] = base[lane + 64 * k];
}

__device__ __forceinline__ float2 h2f2(unsigned int uu) {
    __half2 h;
    *reinterpret_cast<unsigned int*>(&h) = uu;
    return __half22float2(h);
}

// Transforms c in place to q = (ai - C) + b; returns eps*LSE_j(q_j/eps).
__device__ __forceinline__ float row_lse(float4 c[8], float ai, const float* bl, int lane) {
    float m = -3.4e38f;
    #pragma unroll
    for (int k = 0; k < 8; ++k) {
        float4 vv = ((const float4*)bl)[lane + 64 * k];
        c[k].x = (ai - c[k].x) + vv.x;
        c[k].y = (ai - c[k].y) + vv.y;
        c[k].z = (ai - c[k].z) + vv.z;
        c[k].w = (ai - c[k].w) + vv.w;
        m = fmaxf(m, fmaxf(fmaxf(c[k].x, c[k].y), fmaxf(c[k].z, c[k].w)));
    }
    #pragma unroll
    for (int o = 1; o < 64; o <<= 1) m = fmaxf(m, __shfl_xor(m, o, 64));
    float s = 0.0f;
    #pragma unroll
    for (int k = 0; k < 8; ++k)
        s += __expf((c[k].x - m) * INV_EPS) + __expf((c[k].y - m) * INV_EPS) +
             __expf((c[k].z - m) * INV_EPS) + __expf((c[k].w - m) * INV_EPS);
    #pragma unroll
    for (int o = 1; o < 64; o <<= 1) s += __shfl_xor(s, o, 64);
    return EPS * __logf(s) + m;
}

// Online (m,s) merge of one scalar term q (values in C-units, exp scaled by 1/eps)
__device__ __forceinline__ void mergec(float& m, float& s, float q) {
    float nm = fmaxf(m, q);
    s = s * __expf((m - nm) * INV_EPS) + __expf((q - nm) * INV_EPS);
    m = nm;
}
__device__ __forceinline__ void mergems(float& m, float& s, float mo, float so) {
    float nm = fmaxf(m, mo);
    s = s * __expf((m - nm) * INV_EPS) + so * __expf((mo - nm) * INV_EPS);
    m = nm;
}
__device__ __forceinline__ void merge44(float4& m, float4& s, float4 mo, float4 so) {
    mergems(m.x, s.x, mo.x, so.x);
    mergems(m.y, s.y, mo.y, so.y);
    mergems(m.z, s.z, mo.z, so.z);
    mergems(m.w, s.w, mo.w, so.w);
}

__device__ __forceinline__ void merge_row(float4 M[8], float4 S[8],
                                          const float4 q[8], float dr) {
    #pragma unroll
    for (int k = 0; k < 8; ++k) {
        mergec(M[k].x, S[k].x, q[k].x + dr);
        mergec(M[k].y, S[k].y, q[k].y + dr);
        mergec(M[k].z, S[k].z, q[k].z + dr);
        mergec(M[k].w, S[k].w, q[k].w + dr);
    }
}

// ---- fp16-row helpers. Column mapping: lane owns cols 8*(lane+64k)+0..7,
// k=0..3 (one uint4 = 8 halfs per k). bl float4 slots 2g, 2g+1 (g=lane+64k)
// cover cols 8g..8g+3 and 8g+4..8g+7 — same cols/slot as the fp32 layout,
// so the slot-major ps/pm epilogues and v_fast/v_comb are unchanged. ----

// Q[32] = (ai - C16) + v; returns eps*LSE (max-safe). bl holds raw v.
__device__ __forceinline__ float row_lse16(const uint4 H[4], float Q[32], float ai,
                                           const float* bl, int lane) {
    const float4* bl4 = (const float4*)bl;
    float m = -3.4e38f;
    #pragma unroll
    for (int k = 0; k < 4; ++k) {
        int g = lane + 64 * k;
        float2 f0 = h2f2(H[k].x), f1 = h2f2(H[k].y);
        float2 f2 = h2f2(H[k].z), f3 = h2f2(H[k].w);
        float4 v0 = bl4[2 * g], v1 = bl4[2 * g + 1];
        int o = 8 * k;
        Q[o + 0] = (ai - f0.x) + v0.x; Q[o + 1] = (ai - f0.y) + v0.y;
        Q[o + 2] = (ai - f1.x) + v0.z; Q[o + 3] = (ai - f1.y) + v0.w;
        Q[o + 4] = (ai - f2.x) + v1.x; Q[o + 5] = (ai - f2.y) + v1.y;
        Q[o + 6] = (ai - f3.x) + v1.z; Q[o + 7] = (ai - f3.y) + v1.w;
        m = fmaxf(m, fmaxf(fmaxf(fmaxf(Q[o+0],Q[o+1]), fmaxf(Q[o+2],Q[o+3])),
                           fmaxf(fmaxf(Q[o+4],Q[o+5]), fmaxf(Q[o+6],Q[o+7]))));
    }
    #pragma unroll
    for (int o = 1; o < 64; o <<= 1) m = fmaxf(m, __shfl_xor(m, o, 64));
    float s = 0.0f;
    #pragma unroll
    for (int j = 0; j < 32; ++j) s += __expf((Q[j] - m) * INV_EPS);
    #pragma unroll
    for (int o = 1; o < 64; o <<= 1) s += __shfl_xor(s, o, 64);
    return EPS * __logf(s) + m;
}

__device__ __forceinline__ void merge_row16(float M[32], float S[32],
                                            const float Q[32], float dr) {
    #pragma unroll
    for (int j = 0; j < 32; ++j) mergec(M[j], S[j], Q[j] + dr);
}

// X[32] = exp((u - C16 + v)/eps); returns row sum. bl holds v*INV_EPS.
__device__ __forceinline__ float row_sum16(const uint4 H[4], float X[32], float aiv,
                                           const float* bl, int lane) {
    const float4* bl4 = (const float4*)bl;
    float s = 0.0f;
    #pragma unroll
    for (int k = 0; k < 4; ++k) {
        int g = lane + 64 * k;
        float2 f0 = h2f2(H[k].x), f1 = h2f2(H[k].y);
        float2 f2 = h2f2(H[k].z), f3 = h2f2(H[k].w);
        float4 v0 = bl4[2 * g], v1 = bl4[2 * g + 1];
        int o = 8 * k;
        X[o + 0] = __expf(fmaf(f0.x, -INV_EPS, aiv + v0.x));
        X[o + 1] = __expf(fmaf(f0.y, -INV_EPS, aiv + v0.y));
        X[o + 2] = __expf(fmaf(f1.x, -INV_EPS, aiv + v0.z));
        X[o + 3] = __expf(fmaf(f1.y, -INV_EPS, aiv + v0.w));
        X[o + 4] = __expf(fmaf(f2.x, -INV_EPS, aiv + v1.x));
        X[o + 5] = __expf(fmaf(f2.y, -INV_EPS, aiv + v1.y));
        X[o + 6] = __expf(fmaf(f3.x, -INV_EPS, aiv + v1.z));
        X[o + 7] = __expf(fmaf(f3.y, -INV_EPS, aiv + v1.w));
        s += ((X[o+0]+X[o+1])+(X[o+2]+X[o+3])) + ((X[o+4]+X[o+5])+(X[o+6]+X[o+7]));
    }
    #pragma unroll
    for (int o = 1; o < 64; o <<= 1) s += __shfl_xor(s, o, 64);
    return s;
}

// ---------------------------------------------------------------------------
// LEGACY fp32 path (r9-validated, 1032 us) — fallback when ws can't hold C16.
// ---------------------------------------------------------------------------
__global__ __launch_bounds__(256) void iter_pass(const float* __restrict__ C,
                                                 float* __restrict__ u,
                                                 const float* __restrict__ v,
                                                 float* __restrict__ pm,
                                                 float* __restrict__ ps,
                                                 float* __restrict__ errAcc,
                                                 const int* __restrict__ active,
                                                 int t_iter) {
    if (!active[t_iter]) return;
    __shared__ float bl[P2];
    __shared__ float4 LM[4][512];
    __shared__ float4 LS[4][512];
    __shared__ float da_s[4];
    int t = threadIdx.x;
    int n = blockIdx.x >> 7;
    int i0 = (blockIdx.x & (PCHUNKS - 1)) * 16;
    {
        const float4* bsrc = (const float4*)(v + n * P2);
        ((float4*)bl)[t] = bsrc[t];
        ((float4*)bl)[t + 256] = bsrc[t + 256];
    }
    __syncthreads();

    int wave = t >> 6, lane = t & 63;
    int irow = i0 + wave * 4;
    float* arow = u + n * P1 + irow;
    float a0 = arow[0], a1 = arow[1], a2 = arow[2], a3 = arow[3];
    const float4* base = (const float4*)(C + ((size_t)(n * P1 + irow)) * P2);

    float4 M[8], S[8];
    #pragma unroll
    for (int k = 0; k < 8; ++k) {
        M[k] = make_float4(-3.4e38f, -3.4e38f, -3.4e38f, -3.4e38f);
        S[k] = make_float4(0.0f, 0.0f, 0.0f, 0.0f);
    }

    float4 A[8], B[8];
    load_row8(A, base, lane);
    load_row8(B, base + RP, lane);
    float l0 = row_lse(A, a0, bl, lane);
    float d0 = ELOG - l0;
    merge_row(M, S, A, d0);
    load_row8(A, base + 2 * RP, lane);
    float l1 = row_lse(B, a1, bl, lane);
    float d1 = ELOG - l1;
    merge_row(M, S, B, d1);
    load_row8(B, base + 3 * RP, lane);
    float l2 = row_lse(A, a2, bl, lane);
    float d2 = ELOG - l2;
    merge_row(M, S, A, d2);
    float l3 = row_lse(B, a3, bl, lane);
    float d3 = ELOG - l3;
    merge_row(M, S, B, d3);

    if (lane == 0) {
        arow[0] = a0 + d0; arow[1] = a1 + d1;
        arow[2] = a2 + d2; arow[3] = a3 + d3;
        da_s[wave] = fabsf(d0) + fabsf(d1) + fabsf(d2) + fabsf(d3);
    }

    #pragma unroll
    for (int k = 0; k < 8; ++k) {
        LM[wave][lane + 64 * k] = M[k];
        LS[wave][lane + 64 * k] = S[k];
    }
    __syncthreads();

    float4* pm4 = (float4*)pm;
    float4* ps4 = (float4*)ps;
    size_t pb4 = (size_t)blockIdx.x * 512;
    #pragma unroll
    for (int sl = 0; sl < 2; ++sl) {
        int slot = t + 256 * sl;
        float4 m = LM[0][slot], s = LS[0][slot];
        merge44(m, s, LM[1][slot], LS[1][slot]);
        merge44(m, s, LM[2][slot], LS[2][slot]);
        merge44(m, s, LM[3][slot], LS[3][slot]);
        pm4[pb4 + slot] = m;
        ps4[pb4 + slot] = s;
    }

    if (t == 0) {
        atomicAdd(&errAcc[t_iter * ERRSLOTS + (blockIdx.x & (ERRSLOTS - 1))],
                  da_s[0] + da_s[1] + da_s[2] + da_s[3]);
    }
}

// ---------------------------------------------------------------------------
// iter_pass16 (t=0, max-safe, fp16 C): same structure, 16-bit row loads.
// ---------------------------------------------------------------------------
__global__ __launch_bounds__(256) void iter_pass16(const unsigned short* __restrict__ C16,
                                                   float* __restrict__ u,
                                                   const float* __restrict__ v,
                                                   float* __restrict__ pm,
                                                   float* __restrict__ ps,
                                                   float* __restrict__ errAcc,
                                                   const int* __restrict__ active,
                                                   int t_iter) {
    if (!active[t_iter]) return;
    __shared__ float bl[P2];
    __shared__ float4 LM[4][512];
    __shared__ float4 LS[4][512];
    __shared__ float da_s[4];
    int t = threadIdx.x;
    int n = blockIdx.x >> 7;
    int i0 = (blockIdx.x & (PCHUNKS - 1)) * 16;
    {
        const float4* bsrc = (const float4*)(v + n * P2);
        ((float4*)bl)[t] = bsrc[t];
        ((float4*)bl)[t + 256] = bsrc[t + 256];
    }
    __syncthreads();

    int wave = t >> 6, lane = t & 63;
    int irow = i0 + wave * 4;
    float* arow = u + n * P1 + irow;
    float a0 = arow[0], a1 = arow[1], a2 = arow[2], a3 = arow[3];
    const uint4* b16 = (const uint4*)(C16 + ((size_t)(n * P1 + irow)) * P2);

    float M[32], S[32], Q[32];
    #pragma unroll
    for (int j = 0; j < 32; ++j) { M[j] = -3.4e38f; S[j] = 0.0f; }

    uint4 HA[4], HB[4];
    #pragma unroll
    for (int k = 0; k < 4; ++k) HA[k] = b16[lane + 64 * k];
    #pragma unroll
    for (int k = 0; k < 4; ++k) HB[k] = (b16 + RP16)[lane + 64 * k];
    float l0 = row_lse16(HA, Q, a0, bl, lane);
    float d0 = ELOG - l0;
    merge_row16(M, S, Q, d0);
    #pragma unroll
    for (int k = 0; k < 4; ++k) HA[k] = (b16 + 2 * RP16)[lane + 64 * k];
    float l1 = row_lse16(HB, Q, a1, bl, lane);
    float d1 = ELOG - l1;
    merge_row16(M, S, Q, d1);
    #pragma unroll
    for (int k = 0; k < 4; ++k) HB[k] = (b16 + 3 * RP16)[lane + 64 * k];
    float l2 = row_lse16(HA, Q, a2, bl, lane);
    float d2 = ELOG - l2;
    merge_row16(M, S, Q, d2);
    float l3 = row_lse16(HB, Q, a3, bl, lane);
    float d3 = ELOG - l3;
    merge_row16(M, S, Q, d3);

    if (lane == 0) {
        arow[0] = a0 + d0; arow[1] = a1 + d1;
        arow[2] = a2 + d2; arow[3] = a3 + d3;
        da_s[wave] = fabsf(d0) + fabsf(d1) + fabsf(d2) + fabsf(d3);
    }

    #pragma unroll
    for (int k = 0; k < 4; ++k) {
        int g = lane + 64 * k;
        LM[wave][2*g+0] = make_float4(M[8*k+0], M[8*k+1], M[8*k+2], M[8*k+3]);
        LM[wave][2*g+1] = make_float4(M[8*k+4], M[8*k+5], M[8*k+6], M[8*k+7]);
        LS[wave][2*g+0] = make_float4(S[8*k+0], S[8*k+1], S[8*k+2], S[8*k+3]);
        LS[wave][2*g+1] = make_float4(S[8*k+4], S[8*k+5], S[8*k+6], S[8*k+7]);
    }
    __syncthreads();

    float4* pm4 = (float4*)pm;
    float4* ps4 = (float4*)ps;
    size_t pb4 = (size_t)blockIdx.x * 512;
    #pragma unroll
    for (int sl = 0; sl < 2; ++sl) {
        int slot = t + 256 * sl;
        float4 m = LM[0][slot], s = LS[0][slot];
        merge44(m, s, LM[1][slot], LS[1][slot]);
        merge44(m, s, LM[2][slot], LS[2][slot]);
        merge44(m, s, LM[3][slot], LS[3][slot]);
        pm4[pb4 + slot] = m;
        ps4[pb4 + slot] = s;
    }

    if (t == 0) {
        atomicAdd(&errAcc[t_iter * ERRSLOTS + (blockIdx.x & (ERRSLOTS - 1))],
                  da_s[0] + da_s[1] + da_s[2] + da_s[3]);
    }
}

// ---------------------------------------------------------------------------
// v_comb (t=0): merge PCHUNKS (m,s) partials per column, apply v update,
// advance active. Layout identical for fp32/fp16 producers.
// ---------------------------------------------------------------------------
__global__ __launch_bounds__(256) void v_comb(const float* __restrict__ pm,
                                              const float* __restrict__ ps,
                                              float* __restrict__ v,
                                              const float* __restrict__ errAcc,
                                              int* __restrict__ active,
                                              int t_iter) {
    if (blockIdx.x == 0 && threadIdx.x == 0) {
        float e = 0.0f;
        #pragma unroll
        for (int q = 0; q < ERRSLOTS; ++q) e += errAcc[t_iter * ERRSLOTS + q];
        if (active[t_iter] && (e * 0.25f >= THRESH)) active[t_iter + 1] = 1;
    }
    if (!active[t_iter]) return;
    __shared__ float LMv[4][64];
    __shared__ float LSv[4][64];
    int t = threadIdx.x, wave = t >> 6, lane = t & 63;
    int n = blockIdx.x >> 5;
    int j = ((blockIdx.x & 31) << 6) + lane;
    const float* pmb = pm + ((size_t)(n * PCHUNKS + wave * 32)) * P2 + j;
    const float* psb = ps + ((size_t)(n * PCHUNKS + wave * 32)) * P2 + j;
    float m0 = -3.4e38f, s0 = 0.0f, m1 = -3.4e38f, s1 = 0.0f;
    float m2 = -3.4e38f, s2 = 0.0f, m3 = -3.4e38f, s3 = 0.0f;
    #pragma unroll
    for (int c = 0; c < 32; c += 4) {
        mergems(m0, s0, pmb[(size_t)(c + 0) * P2], psb[(size_t)(c + 0) * P2]);
        mergems(m1, s1, pmb[(size_t)(c + 1) * P2], psb[(size_t)(c + 1) * P2]);
        mergems(m2, s2, pmb[(size_t)(c + 2) * P2], psb[(size_t)(c + 2) * P2]);
        mergems(m3, s3, pmb[(size_t)(c + 3) * P2], psb[(size_t)(c + 3) * P2]);
    }
    mergems(m0, s0, m1, s1);
    mergems(m2, s2, m3, s3);
    mergems(m0, s0, m2, s2);
    LMv[wave][lane] = m0; LSv[wave][lane] = s0;
    __syncthreads();
    if (wave == 0) {
        float m = LMv[0][lane], s = LSv[0][lane];
        mergems(m, s, LMv[1][lane], LSv[1][lane]);
        mergems(m, s, LMv[2][lane], LSv[2][lane]);
        mergems(m, s, LMv[3][lane], LSv[3][lane]);
        float lse = EPS * __logf(s) + m;
        v[n * P2 + j] = v[n * P2 + j] + ELOG - lse;
    }
}

// ---------------------------------------------------------------------------
// FAST PATH (t >= 1). Invariants (r5): after t=0's full (u,v) update on the
// SAME cost matrix the iterations use, row/col sums stay in fp32 range.
// ---------------------------------------------------------------------------
__device__ __forceinline__ float row_sum(float4 c[8], float aiv, const float* bl,
                                         int lane) {
    float s = 0.0f;
    #pragma unroll
    for (int k = 0; k < 8; ++k) {
        float4 vv = ((const float4*)bl)[lane + 64 * k];
        c[k].x = __expf(fmaf(c[k].x, -INV_EPS, aiv + vv.x));
        c[k].y = __expf(fmaf(c[k].y, -INV_EPS, aiv + vv.y));
        c[k].z = __expf(fmaf(c[k].z, -INV_EPS, aiv + vv.z));
        c[k].w = __expf(fmaf(c[k].w, -INV_EPS, aiv + vv.w));
        s += (c[k].x + c[k].y) + (c[k].z + c[k].w);
    }
    #pragma unroll
    for (int o = 1; o < 64; o <<= 1) s += __shfl_xor(s, o, 64);
    return s;
}

__device__ __forceinline__ void acc_row(float4 S[8], const float4 q[8], float ed) {
    #pragma unroll
    for (int k = 0; k < 8; ++k) {
        S[k].x = fmaf(q[k].x, ed, S[k].x);
        S[k].y = fmaf(q[k].y, ed, S[k].y);
        S[k].z = fmaf(q[k].z, ed, S[k].z);
        S[k].w = fmaf(q[k].w, ed, S[k].w);
    }
}

// Legacy fp32 iter_fast (r9): 512 threads, 8 waves, 2 rows/wave.
__global__ __launch_bounds__(512) void iter_fast(const float* __restrict__ C,
                                                 float* __restrict__ u,
                                                 const float* __restrict__ v,
                                                 float* __restrict__ ps,
                                                 float* __restrict__ errAcc,
                                                 const int* __restrict__ active,
                                                 int t_iter) {
    if (!active[t_iter]) return;
    __shared__ float bl[P2];
    __shared__ float4 LS[8][512];
    __shared__ float da_s[8];
    int t = threadIdx.x;
    int n = blockIdx.x >> 7;
    int i0 = (blockIdx.x & (PCHUNKS - 1)) * 16;
    {
        const float4* bsrc = (const float4*)(v + n * P2);
        float4 b0 = bsrc[t];
        b0.x *= INV_EPS; b0.y *= INV_EPS; b0.z *= INV_EPS; b0.w *= INV_EPS;
        ((float4*)bl)[t] = b0;
    }
    __syncthreads();

    int wave = t >> 6, lane = t & 63;
    int irow = i0 + wave * 2;
    float* arow = u + n * P1 + irow;
    float a0 = arow[0], a1 = arow[1];
    const float4* base = (const float4*)(C + ((size_t)(n * P1 + irow)) * P2);

    float4 S[8];
    #pragma unroll
    for (int k = 0; k < 8; ++k) S[k] = make_float4(0.0f, 0.0f, 0.0f, 0.0f);

    float4 X[8], Y[8];
    load_row8(X, base, lane);
    load_row8(Y, base + RP, lane);
    float s0 = row_sum(X, a0 * INV_EPS, bl, lane);
    float d0 = ELOG - EPS * __logf(s0);
    acc_row(S, X, __fdividef(MU_VAL, s0));
    float s1 = row_sum(Y, a1 * INV_EPS, bl, lane);
    float d1 = ELOG - EPS * __logf(s1);
    acc_row(S, Y, __fdividef(MU_VAL, s1));

    if (lane == 0) {
        arow[0] = a0 + d0; arow[1] = a1 + d1;
        da_s[wave] = fabsf(d0) + fabsf(d1);
    }

    #pragma unroll
    for (int k = 0; k < 8; ++k) LS[wave][lane + 64 * k] = S[k];
    __syncthreads();

    float4* ps4 = (float4*)ps;
    size_t pb4 = (size_t)blockIdx.x * 512;
    {
        int slot = t;
        float4 x0 = LS[0][slot], x1 = LS[1][slot];
        float4 x2 = LS[2][slot], x3 = LS[3][slot];
        float4 x4 = LS[4][slot], x5 = LS[5][slot];
        float4 x6 = LS[6][slot], x7 = LS[7][slot];
        float4 o;
        o.x = ((x0.x + x1.x) + (x2.x + x3.x)) + ((x4.x + x5.x) + (x6.x + x7.x));
        o.y = ((x0.y + x1.y) + (x2.y + x3.y)) + ((x4.y + x5.y) + (x6.y + x7.y));
        o.z = ((x0.z + x1.z) + (x2.z + x3.z)) + ((x4.z + x5.z) + (x6.z + x7.z));
        o.w = ((x0.w + x1.w) + (x2.w + x3.w)) + ((x4.w + x5.w) + (x6.w + x7.w));
        ps4[pb4 + slot] = o;
    }

    if (t == 0) {
        atomicAdd(&errAcc[t_iter * ERRSLOTS + (blockIdx.x & (ERRSLOTS - 1))],
                  ((da_s[0] + da_s[1]) + (da_s[2] + da_s[3])) +
                  ((da_s[4] + da_s[5]) + (da_s[6] + da_s[7])));
    }
}

// fp16 iter_fast: identical structure, half the row bytes (8 loads/row-pair
// instead of 16 at the same in-flight request count -> ~2x row rate).
__global__ __launch_bounds__(512) void iter_fast16(const unsigned short* __restrict__ C16,
                                                   float* __restrict__ u,
                                                   const float* __restrict__ v,
                                                   float* __restrict__ ps,
                                                   float* __restrict__ errAcc,
                                                   const int* __restrict__ active,
                                                   int t_iter) {
    if (!active[t_iter]) return;
    __shared__ float bl[P2];          // 8 KB: v*INV_EPS
    __shared__ float4 LS[8][512];     // 64 KB: per-wave column sums
    __shared__ float da_s[8];
    int t = threadIdx.x;              // 0..511
    int n = blockIdx.x >> 7;
    int i0 = (blockIdx.x & (PCHUNKS - 1)) * 16;
    {
        const float4* bsrc = (const float4*)(v + n * P2);
        float4 b0 = bsrc[t];
        b0.x *= INV_EPS; b0.y *= INV_EPS; b0.z *= INV_EPS; b0.w *= INV_EPS;
        ((float4*)bl)[t] = b0;
    }
    __syncthreads();

    int wave = t >> 6, lane = t & 63;
    int irow = i0 + wave * 2;
    float* arow = u + n * P1 + irow;
    float a0 = arow[0], a1 = arow[1];
    const uint4* b16 = (const uint4*)(C16 + ((size_t)(n * P1 + irow)) * P2);

    float S[32], X[32];
    #pragma unroll
    for (int j = 0; j < 32; ++j) S[j] = 0.0f;

    uint4 HA[4], HB[4];
    #pragma unroll
    for (int k = 0; k < 4; ++k) HA[k] = b16[lane + 64 * k];
    #pragma unroll
    for (int k = 0; k < 4; ++k) HB[k] = (b16 + RP16)[lane + 64 * k];
    float s0 = row_sum16(HA, X, a0 * INV_EPS, bl, lane);
    float d0 = ELOG - EPS * __logf(s0);
    float e0 = __fdividef(MU_VAL, s0);
    #pragma unroll
    for (int j = 0; j < 32; ++j) S[j] = fmaf(X[j], e0, S[j]);
    float s1 = row_sum16(HB, X, a1 * INV_EPS, bl, lane);
    float d1 = ELOG - EPS * __logf(s1);
    float e1 = __fdividef(MU_VAL, s1);
    #pragma unroll
    for (int j = 0; j < 32; ++j) S[j] = fmaf(X[j], e1, S[j]);

    if (lane == 0) {
        arow[0] = a0 + d0; arow[1] = a1 + d1;
        da_s[wave] = fabsf(d0) + fabsf(d1);
    }

    #pragma unroll
    for (int k = 0; k < 4; ++k) {
        int g = lane + 64 * k;
        LS[wave][2*g+0] = make_float4(S[8*k+0], S[8*k+1], S[8*k+2], S[8*k+3]);
        LS[wave][2*g+1] = make_float4(S[8*k+4], S[8*k+5], S[8*k+6], S[8*k+7]);
    }
    __syncthreads();

    float4* ps4 = (float4*)ps;
    size_t pb4 = (size_t)blockIdx.x * 512;
    {
        int slot = t;
        float4 x0 = LS[0][slot], x1 = LS[1][slot];
        float4 x2 = LS[2][slot], x3 = LS[3][slot];
        float4 x4 = LS[4][slot], x5 = LS[5][slot];
        float4 x6 = LS[6][slot], x7 = LS[7][slot];
        float4 o;
        o.x = ((x0.x + x1.x) + (x2.x + x3.x)) + ((x4.x + x5.x) + (x6.x + x7.x));
        o.y = ((x0.y + x1.y) + (x2.y + x3.y)) + ((x4.y + x5.y) + (x6.y + x7.y));
        o.z = ((x0.z + x1.z) + (x2.z + x3.z)) + ((x4.z + x5.z) + (x6.z + x7.z));
        o.w = ((x0.w + x1.w) + (x2.w + x3.w)) + ((x4.w + x5.w) + (x6.w + x7.w));
        ps4[pb4 + slot] = o;
    }

    if (t == 0) {
        atomicAdd(&errAcc[t_iter * ERRSLOTS + (blockIdx.x & (ERRSLOTS - 1))],
                  ((da_s[0] + da_s[1]) + (da_s[2] + da_s[3])) +
                  ((da_s[4] + da_s[5]) + (da_s[6] + da_s[7])));
    }
}

// v_fast: plain-sum merge of PCHUNKS=128 partials per column, v update,
// advance active (shared by fp32/fp16 paths).
__global__ __launch_bounds__(256) void v_fast(const float* __restrict__ ps,
                                              float* __restrict__ v,
                                              const float* __restrict__ errAcc,
                                              int* __restrict__ active,
                                              int t_iter) {
    if (blockIdx.x == 0 && threadIdx.x == 0) {
        float e = 0.0f;
        #pragma unroll
        for (int q = 0; q < ERRSLOTS; ++q) e += errAcc[t_iter * ERRSLOTS + q];
        if (active[t_iter] && (e * 0.25f >= THRESH)) active[t_iter + 1] = 1;
    }
    if (!active[t_iter]) return;
    __shared__ float LSv[4][64];
    int t = threadIdx.x, wave = t >> 6, lane = t & 63;
    int n = blockIdx.x >> 5;
    int j = ((blockIdx.x & 31) << 6) + lane;
    const float* psb = ps + ((size_t)(n * PCHUNKS + wave * 32)) * P2 + j;
    float s0 = 0.0f, s1 = 0.0f, s2 = 0.0f, s3 = 0.0f;
    #pragma unroll
    for (int c = 0; c < 32; c += 4) {
        s0 += psb[(size_t)(c + 0) * P2];
        s1 += psb[(size_t)(c + 1) * P2];
        s2 += psb[(size_t)(c + 2) * P2];
        s3 += psb[(size_t)(c + 3) * P2];
    }
    LSv[wave][lane] = (s0 + s1) + (s2 + s3);
    __syncthreads();
    if (wave == 0) {
        float s = (LSv[0][lane] + LSv[1][lane]) + (LSv[2][lane] + LSv[3][lane]);
        v[n * P2 + j] = v[n * P2 + j] + ELOG - EPS * __logf(s);
    }
}

// ---------------------------------------------------------------------------
// final_pass (legacy fp32, r9) and final_pass16 (delta-consistent fp16):
// pi = exp((u - C + v)/eps), cost = sum(pi * C).
// ---------------------------------------------------------------------------
__device__ __forceinline__ float row_pi(const float4 c[8], float ui, const float* vl,
                                        int lane, float4* prow) {
    float acc = 0.0f;
    #pragma unroll
    for (int k = 0; k < 8; ++k) {
        float4 vv = ((const float4*)vl)[lane + 64 * k];
        float4 p;
        p.x = __expf(((ui - c[k].x) + vv.x) * INV_EPS);
        p.y = __expf(((ui - c[k].y) + vv.y) * INV_EPS);
        p.z = __expf(((ui - c[k].z) + vv.z) * INV_EPS);
        p.w = __expf(((ui - c[k].w) + vv.w) * INV_EPS);
        prow[lane + 64 * k] = p;
        acc += p.x * c[k].x + p.y * c[k].y + p.z * c[k].z + p.w * c[k].w;
    }
    return acc;
}

__global__ __launch_bounds__(512) void final_pass(const float* __restrict__ C,
                                                  const float* __restrict__ u,
                                                  const float* __restrict__ v,
                                                  float* __restrict__ pi,
                                                  float* __restrict__ cost) {
    __shared__ float vl[P2];
    __shared__ float red[8];
    int t = threadIdx.x;
    int n = blockIdx.x >> 7;
    int i0 = (blockIdx.x & 127) * 16;
    {
        const float4* vsrc = (const float4*)(v + n * P2);
        ((float4*)vl)[t] = vsrc[t];
    }
    __syncthreads();

    int wave = t >> 6, lane = t & 63;
    int irow = i0 + wave * 2;
    const float* urow = u + n * P1 + irow;
    float u0 = urow[0], u1 = urow[1];
    const float4* base = (const float4*)(C + ((size_t)(n * P1 + irow)) * P2);
    float4* pbase = (float4*)(pi + ((size_t)(n * P1 + irow)) * P2);

    float4 A[8], B[8];
    load_row8(A, base, lane);
    load_row8(B, base + RP, lane);
    float acc = row_pi(A, u0, vl, lane, pbase);
    acc += row_pi(B, u1, vl, lane, pbase + RP);

    #pragma unroll
    for (int o = 1; o < 64; o <<= 1) acc += __shfl_xor(acc, o, 64);
    if (lane == 0) red[wave] = acc;
    __syncthreads();
    if (t == 0) {
        atomicAdd(&cost[n], ((red[0] + red[1]) + (red[2] + red[3])) +
                            ((red[4] + red[5]) + (red[6] + red[7])));
    }
}

__device__ __forceinline__ float row_pi16(const uint4 H[4], float ui, const float* vl,
                                          int lane, float4* prow) {
    const float4* bl4 = (const float4*)vl;
    float acc = 0.0f;
    #pragma unroll
    for (int k = 0; k < 4; ++k) {
        int g = lane + 64 * k;
        float2 f0 = h2f2(H[k].x), f1 = h2f2(H[k].y);
        float2 f2 = h2f2(H[k].z), f3 = h2f2(H[k].w);
        float4 v0 = bl4[2 * g], v1 = bl4[2 * g + 1];
        float p0 = __expf(((ui - f0.x) + v0.x) * INV_EPS);
        float p1 = __expf(((ui - f0.y) + v0.y) * INV_EPS);
        float p2 = __expf(((ui - f1.x) + v0.z) * INV_EPS);
        float p3 = __expf(((ui - f1.y) + v0.w) * INV_EPS);
        float p4 = __expf(((ui - f2.x) + v1.x) * INV_EPS);
        float p5 = __expf(((ui - f2.y) + v1.y) * INV_EPS);
        float p6 = __expf(((ui - f3.x) + v1.z) * INV_EPS);
        float p7 = __expf(((ui - f3.y) + v1.w) * INV_EPS);
        prow[2 * g + 0] = make_float4(p0, p1, p2, p3);
        prow[2 * g + 1] = make_float4(p4, p5, p6, p7);
        acc += ((p0 * f0.x + p1 * f0.y) + (p2 * f1.x + p3 * f1.y)) +
               ((p4 * f2.x + p5 * f2.y) + (p6 * f3.x + p7 * f3.y));
    }
    return acc;
}

__global__ __launch_bounds__(512) void final_pass16(const unsigned short* __restrict__ C16,
                                                    const float* __restrict__ u,
                                                    const float* __restrict__ v,
                                                    float* __restrict__ pi,
                                                    float* __restrict__ cost) {
    __shared__ float vl[P2];
    __shared__ float red[8];
    int t = threadIdx.x;
    int n = blockIdx.x >> 7;
    int i0 = (blockIdx.x & 127) * 16;
    {
        const float4* vsrc = (const float4*)(v + n * P2);
        ((float4*)vl)[t] = vsrc[t];
    }
    __syncthreads();

    int wave = t >> 6, lane = t & 63;
    int irow = i0 + wave * 2;
    const float* urow = u + n * P1 + irow;
    float u0 = urow[0], u1 = urow[1];
    const uint4* b16 = (const uint4*)(C16 + ((size_t)(n * P1 + irow)) * P2);
    float4* pbase = (float4*)(pi + ((size_t)(n * P1 + irow)) * P2);

    uint4 HA[4], HB[4];
    #pragma unroll
    for (int k = 0; k < 4; ++k) HA[k] = b16[lane + 64 * k];
    #pragma unroll
    for (int k = 0; k < 4; ++k) HB[k] = (b16 + RP16)[lane + 64 * k];
    float acc = row_pi16(HA, u0, vl, lane, pbase);
    acc += row_pi16(HB, u1, vl, lane, pbase + RP);

    #pragma unroll
    for (int o = 1; o < 64; o <<= 1) acc += __shfl_xor(acc, o, 64);
    if (lane == 0) red[wave] = acc;
    __syncthreads();
    if (t == 0) {
        atomicAdd(&cost[n], ((red[0] + red[1]) + (red[2] + red[3])) +
                            ((red[4] + red[5]) + (red[6] + red[7])));
    }
}

// ---------------------------------------------------------------------------
extern "C" void kernel_launch(void* const* d_in, const int* in_sizes, int n_in,
                              void* d_out, int out_size, void* d_ws, size_t ws_size,
                              hipStream_t stream) {
    const float* x = (const float*)d_in[0];   // [N,P1,D]
    const float* y = (const float*)d_in[1];   // [N,P2,D]
    const float* M = (const float*)d_in[2];   // [D,D]
    float* out = (float*)d_out;
    float* cost = out;                                    // [N]
    float* pi = out + NB;                                 // [N,P1,P2]
    float* C = out + NB + (size_t)NB * P1 * P2;           // [N,P1,P2]

    float* ws = (float*)d_ws;
    float* S      = ws;                                   // 4096
    float* xS     = S + DD * DD;                          // N*P1*D
    float* dx     = xS + (size_t)NB * P1 * DD;            // N*P1
    float* dy     = dx + NB * P1;                         // N*P2
    float* u      = dy + NB * P2;                         // N*P1
    float* v      = u + NB * P1;                          // N*P2
    float* errAcc = v + NB * P2;                          // ITER*ERRSLOTS
    int*   active = (int*)(errAcc + ITER * ERRSLOTS);     // 64 ints
    float* ws_end = (float*)(active + 64);

    // pm/ps (8.4 MB): prefer ws, fall back to the dead pi region.
    // C16 (33.5 MB): only if ws also has room; else run the full fp32
    // legacy path (never mix: delta-consistency requires iterations AND
    // final pass to use the same cost matrix). All branches launch-constant.
    size_t base_floats = (size_t)(ws_end - ws);
    size_t pmps_floats = 2 * (size_t)NB * PCHUNKS * P2;   // 2M floats
    bool ws_pmps = ws_size >= (base_floats + pmps_floats) * sizeof(float);
    float* pm;
    float* ps;
    if (ws_pmps) {
        pm = ws_end;
        ps = ws_end + pmps_floats / 2;
    } else {
        pm = pi;
        ps = pi + pmps_floats / 2;
    }
    size_t c16_off = (base_floats + pmps_floats + 3) & ~(size_t)3;  // 16B align
    size_t c16_floats = (size_t)NB * P1 * P2 / 2;         // halfs/2 = 8.4M floats
    bool use16 = ws_pmps && ws_size >= (c16_off + c16_floats) * sizeof(float);
    unsigned short* C16 = use16 ? (unsigned short*)(ws + c16_off) : nullptr;

    prep0<<<1, 256, 0, stream>>>(M, S, errAcc, active, cost);
    prep1<<<(NB * (P1 + P2)) / 4, 256, 0, stream>>>(x, y, S, xS, dx, dy, u, v);
    gemmC<<<dim3(P2 / 64, P1 / 64, NB), 256, 0, stream>>>(xS, y, dx, dy, C, C16);

    if (use16) {
        // Entire Sinkhorn + pi/cost on C16 (delta-consistent).
        iter_pass16<<<NB * PCHUNKS, 256, 0, stream>>>(C16, u, v, pm, ps, errAcc,
                                                      active, 0);
        v_comb<<<NB * 32, 256, 0, stream>>>(pm, ps, v, errAcc, active, 0);
        for (int t = 1; t < ITER; ++t) {
            iter_fast16<<<NB * PCHUNKS, 512, 0, stream>>>(C16, u, v, ps, errAcc,
                                                          active, t);
            v_fast<<<NB * 32, 256, 0, stream>>>(ps, v, errAcc, active, t);
        }
        final_pass16<<<NB * P1 / 16, 512, 0, stream>>>(C16, u, v, pi, cost);
    } else {
        // r9-validated fp32 path.
        iter_pass<<<NB * PCHUNKS, 256, 0, stream>>>(C, u, v, pm, ps, errAcc,
                                                    active, 0);
        v_comb<<<NB * 32, 256, 0, stream>>>(pm, ps, v, errAcc, active, 0);
        for (int t = 1; t < ITER; ++t) {
            iter_fast<<<NB * PCHUNKS, 512, 0, stream>>>(C, u, v, ps, errAcc,
                                                        active, t);
            v_fast<<<NB * 32, 256, 0, stream>>>(ps, v, errAcc, active, t);
        }
        final_pass<<<NB * P1 / 16, 512, 0, stream>>>(C, u, v, pi, cost);
    }
}